// Round 1
// baseline (808.269 us; speedup 1.0000x reference)
//
#include <hip/hip_runtime.h>
#include <math.h>

#define N 8192
#define IN_F 512
#define OUTF 64
#define TI 16
#define JSPLIT 4
#define JRANGE (N / JSPLIT)

// workspace layout (in floats)
#define OFF_H    0u          // 8192*64   = 524288
#define OFF_S    524288u     // 8192
#define OFF_T    532480u     // 8192
#define OFF_TMAX 540672u     // 1 (padded to 16)
#define OFF_SP   540688u     // JSPLIT*8192 = 32768
#define OFF_ACC  573456u     // JSPLIT*524288 = 2097152  -> total 2670608 floats (~10.7 MB)

// ---------------------------------------------------------------------------
// K1: h = input @ W  (8192x512 @ 512x64), s = h@a1, t = h@a2
// 1 wave per block, 8 rows per wave. lane = output column.
// ---------------------------------------------------------------------------
__global__ __launch_bounds__(64) void k_precompute(
    const float* __restrict__ input, const float* __restrict__ W,
    const float* __restrict__ a, float* __restrict__ h,
    float* __restrict__ s, float* __restrict__ t) {
  const int lane = threadIdx.x;
  const int i0 = blockIdx.x * 8;

  float acc[8];
  #pragma unroll
  for (int r = 0; r < 8; r++) acc[r] = 0.f;

  for (int c = 0; c < IN_F; c += 4) {
    const float w0 = W[(c + 0) * OUTF + lane];
    const float w1 = W[(c + 1) * OUTF + lane];
    const float w2 = W[(c + 2) * OUTF + lane];
    const float w3 = W[(c + 3) * OUTF + lane];
    #pragma unroll
    for (int r = 0; r < 8; r++) {
      const float4 iv = *(const float4*)(input + (size_t)(i0 + r) * IN_F + c);
      acc[r] += iv.x * w0 + iv.y * w1 + iv.z * w2 + iv.w * w3;
    }
  }

  const float a1v = a[lane];
  const float a2v = a[OUTF + lane];
  #pragma unroll
  for (int r = 0; r < 8; r++) {
    h[(size_t)(i0 + r) * OUTF + lane] = acc[r];
    float sv = acc[r] * a1v;
    float tv = acc[r] * a2v;
    #pragma unroll
    for (int off = 1; off < 64; off <<= 1) {
      sv += __shfl_xor(sv, off);
      tv += __shfl_xor(tv, off);
    }
    if (lane == 0) {
      s[i0 + r] = sv;
      t[i0 + r] = tv;
    }
  }
}

// ---------------------------------------------------------------------------
// K1.5: tmax = max(t)
// ---------------------------------------------------------------------------
__global__ __launch_bounds__(1024) void k_tmax(const float* __restrict__ t,
                                               float* __restrict__ tmax) {
  __shared__ float red[16];
  const int tid = threadIdx.x;
  float m = -1e30f;
  for (int idx = tid; idx < N; idx += 1024) m = fmaxf(m, t[idx]);
  #pragma unroll
  for (int off = 1; off < 64; off <<= 1) m = fmaxf(m, __shfl_xor(m, off));
  if ((tid & 63) == 0) red[tid >> 6] = m;
  __syncthreads();
  if (tid < 16) {
    m = red[tid];
    #pragma unroll
    for (int off = 1; off < 16; off <<= 1) m = fmaxf(m, __shfl_xor(m, off));
    if (tid == 0) *tmax = m;
  }
}

// ---------------------------------------------------------------------------
// K2: masked-softmax attention, unnormalized partial sums.
// One wave per block. Wave owns TI=16 rows x 64 cols, one j-split range.
// Fixed per-row max bound M_r (no online rescale; partials addable).
// ---------------------------------------------------------------------------
__global__ __launch_bounds__(64) void k_attn(
    const float* __restrict__ h, const float* __restrict__ s,
    const float* __restrict__ t, const float* __restrict__ tmaxp,
    const float* __restrict__ W_si, const float* __restrict__ W_ei,
    const float* __restrict__ adj_ad, const int* __restrict__ adj,
    float* __restrict__ SP, float* __restrict__ accP) {
  const int lane = threadIdx.x;
  const int wid = blockIdx.x;
  const int split = wid & (JSPLIT - 1);
  const int i0 = (wid >> 2) * TI;
  const int jb = split * JRANGE;

  const float aei = fabsf(W_ei[0]);
  const float asi = fabsf(W_si[0]);
  const float tm = *tmaxp;

  float sr[TI], Mr[TI];
  #pragma unroll
  for (int r = 0; r < TI; r++) {
    sr[r] = s[i0 + r];
    const float xm = sr[r] + tm;
    Mr[r] = aei * fmaxf(xm, 0.2f * xm) + asi;  // upper bound on e over the row
  }

  float S[TI], acc[TI];
  #pragma unroll
  for (int r = 0; r < TI; r++) { S[r] = 0.f; acc[r] = 0.f; }

  // p-tile: logical pT[jj][r], rows of 16 floats, chunk-XOR-swizzled
  __shared__ __align__(16) float pT[64 * TI];

  const int swl = (lane >> 1) & 3;  // write-side swizzle for this lane (=jj)

  for (int jt = 0; jt < JRANGE; jt += 64) {
    const int j0 = jb + jt;

    // ---- Phase A: lane = jj. Compute p for 16 rows, store to LDS. ----
    const float tl = t[j0 + lane];
    float pb[4];
    #pragma unroll
    for (int r = 0; r < TI; r++) {
      const size_t gidx = (size_t)(i0 + r) * N + j0 + lane;
      const float d = adj_ad[gidx];
      const int mk = adj[gidx];
      const float x = sr[r] + tl;
      const float e = aei * fmaxf(x, 0.2f * x) + asi * d;
      const float p = (mk > 0) ? __expf(e - Mr[r]) : 0.f;
      S[r] += p;
      pb[r & 3] = p;
      if ((r & 3) == 3) {
        const int chunk = (r >> 2) ^ swl;
        *(float4*)&pT[lane * TI + (chunk << 2)] =
            make_float4(pb[0], pb[1], pb[2], pb[3]);
      }
    }

    // ---- Preload h tile into registers: hreg[jj] = h[j0+jj][lane] ----
    float hreg[64];
    #pragma unroll
    for (int jj = 0; jj < 64; jj++)
      hreg[jj] = h[(size_t)(j0 + jj) * OUTF + lane];

    // ---- Phase B: lane = col. acc[r] += p[r][jj] * h[jj][lane] ----
    #pragma unroll
    for (int jj = 0; jj < 64; jj++) {
      const int sw = (jj >> 1) & 3;
      #pragma unroll
      for (int c = 0; c < 4; c++) {
        const float4 p4 = *(const float4*)&pT[jj * TI + (((c ^ sw)) << 2)];
        acc[c * 4 + 0] += p4.x * hreg[jj];
        acc[c * 4 + 1] += p4.y * hreg[jj];
        acc[c * 4 + 2] += p4.z * hreg[jj];
        acc[c * 4 + 3] += p4.w * hreg[jj];
      }
    }
  }

  // ---- Epilogue: reduce S across lanes, write partials ----
  #pragma unroll
  for (int r = 0; r < TI; r++) {
    float sv = S[r];
    #pragma unroll
    for (int off = 1; off < 64; off <<= 1) sv += __shfl_xor(sv, off);
    if (lane == 0) SP[(size_t)split * N + i0 + r] = sv;
    accP[(size_t)split * (N * OUTF) + (size_t)(i0 + r) * OUTF + lane] = acc[r];
  }
}

// ---------------------------------------------------------------------------
// K3: combine j-split partials, normalize, elu.
// ---------------------------------------------------------------------------
__global__ __launch_bounds__(256) void k_combine(const float* __restrict__ accP,
                                                 const float* __restrict__ SP,
                                                 float* __restrict__ out) {
  const int idx = blockIdx.x * 256 + threadIdx.x;
  const int i = idx >> 6;
  float num = 0.f, den = 0.f;
  #pragma unroll
  for (int sp = 0; sp < JSPLIT; sp++) {
    num += accP[(size_t)sp * (N * OUTF) + idx];
    den += SP[(size_t)sp * N + i];
  }
  const float x = num / den;
  out[idx] = x > 0.f ? x : expm1f(x);
}

// ---------------------------------------------------------------------------
extern "C" void kernel_launch(void* const* d_in, const int* in_sizes, int n_in,
                              void* d_out, int out_size, void* d_ws, size_t ws_size,
                              hipStream_t stream) {
  const float* input  = (const float*)d_in[0];
  const float* W      = (const float*)d_in[1];
  const float* a      = (const float*)d_in[2];
  const float* W_si   = (const float*)d_in[3];
  const float* W_ei   = (const float*)d_in[4];
  const float* adj_ad = (const float*)d_in[5];
  const int*   adj    = (const int*)d_in[6];
  float* out = (float*)d_out;
  float* ws  = (float*)d_ws;

  float* h    = ws + OFF_H;
  float* s    = ws + OFF_S;
  float* t    = ws + OFF_T;
  float* tmax = ws + OFF_TMAX;
  float* SP   = ws + OFF_SP;
  float* accP = ws + OFF_ACC;

  k_precompute<<<N / 8, 64, 0, stream>>>(input, W, a, h, s, t);
  k_tmax<<<1, 1024, 0, stream>>>(t, tmax);
  k_attn<<<(N / TI) * JSPLIT, 64, 0, stream>>>(h, s, t, tmax, W_si, W_ei,
                                               adj_ad, adj, SP, accP);
  k_combine<<<(N * OUTF) / 256, 256, 0, stream>>>(accP, SP, out);
}